// Round 4
// baseline (863.346 us; speedup 1.0000x reference)
//
#include <hip/hip_runtime.h>
#include <hip/hip_bf16.h>

#define BATCH 8
#define CDIM 192
#define HEADS 8
#define CH 24
#define HH 128
#define WW 128
#define NPIX (HH*WW)                  // 16384
#define NELEM (BATCH*CDIM*NPIX)       // 25165824
#define NP4 (NPIX/4)                  // 4096

#define NSLAB 128                     // one gram partial per image row
#define NJOBS 624                     // 576 cross dots + 24 q self + 24 k self

typedef __attribute__((ext_vector_type(8))) short bf16x8;
typedef __attribute__((ext_vector_type(4))) float f32x4;

// ---------------------------------------------------------------------------
// Static pool (96 MiB units).
// ---------------------------------------------------------------------------
#define UNIT 100663296ull   // NELEM*4 bytes == 2*NELEM bf16 elements
__device__ __align__(256) unsigned char g_pool[6 * UNIT + (25u << 20)];

#define OFF_XF   (0 * UNIT)
#define OFF_YF   (1 * UNIT)
#define OFF_T0Q  (2 * UNIT)
#define OFF_T0K  (3 * UNIT)
#define OFF_VF   (4 * UNIT)
#define OFF_T0V  (5 * UNIT)
#define OFF_MISC (6 * UNIT)
#define OFF_PART (OFF_MISC)                            // 64*128*624*4 = 20447232
#define OFF_S    (OFF_MISC + 20447232ull)              // 64*624*4    = 159744
#define OFF_M    (OFF_S + 159744ull)                   // 8*192*192*4 = 1179648
#define OFF_MF   (OFF_M + 1179648ull)                  // hi+lo bf16  = 1179648

// round-to-nearest-even fp32 -> bf16 (bit pattern)
__device__ inline unsigned short bf_rne(float x) {
  unsigned u = __float_as_uint(x);
  unsigned r = (u + 0x7fffu + ((u >> 16) & 1u)) >> 16;
  return (unsigned short)r;
}
__device__ inline void f32_split(float x, unsigned short& h, unsigned short& l) {
  h = bf_rne(x);
  float hf = __uint_as_float(((unsigned)h) << 16);
  l = bf_rne(x - hf);
}

// ---------------------------------------------------------------------------
// Weight/M -> A-fragment layout (hi at base, lo at +nb*CDIM*CDIM elems).
// ---------------------------------------------------------------------------
__global__ __launch_bounds__(64) void w_to_frag(const float* __restrict__ W,
                                                unsigned short* __restrict__ F,
                                                int nb) {
  const int b = blockIdx.x / 12, mf = blockIdx.x % 12;
  const int lane = threadIdx.x;
  const int row = mf * 16 + (lane & 15);
  const size_t lo = (size_t)nb * CDIM * CDIM;
#pragma unroll
  for (int ks = 0; ks < 6; ++ks) {
    const int k0 = ks * 32 + (lane >> 4) * 8;
    const float* src = W + ((size_t)b * CDIM + row) * CDIM + k0;
    bf16x8 hv, lv;
#pragma unroll
    for (int j = 0; j < 8; ++j) {
      unsigned short h, l;
      f32_split(src[j], h, l);
      hv[j] = (short)h;
      lv[j] = (short)l;
    }
    const size_t didx = (((size_t)(blockIdx.x) * 6 + ks) * 64 + lane) * 8;
    *(bf16x8*)(F + didx) = hv;
    *(bf16x8*)(F + lo + didx) = lv;
  }
}

// ---------------------------------------------------------------------------
// Activation -> B-fragment layout (for the two network inputs x,y).
// ---------------------------------------------------------------------------
__global__ __launch_bounds__(256) void x_to_frag(const float* __restrict__ X,
                                                 unsigned short* __restrict__ F) {
  const int gid = blockIdx.x * 256 + threadIdx.x;
  const int p4 = gid & (NP4 - 1);
  const int kb = (gid >> 12) % 24;
  const int b = gid / (NP4 * 24);
  const size_t lo = (size_t)BATCH * CDIM * NPIX;

  float4 v[8];
#pragma unroll
  for (int j = 0; j < 8; ++j)
    v[j] = *(const float4*)(X + ((size_t)(b * CDIM + kb * 8 + j)) * NPIX + p4 * 4);

#pragma unroll
  for (int pp = 0; pp < 4; ++pp) {
    bf16x8 hv, lv;
#pragma unroll
    for (int j = 0; j < 8; ++j) {
      const float* vv = (const float*)&v[j];
      unsigned short h, l;
      f32_split(vv[pp], h, l);
      hv[j] = (short)h;
      lv[j] = (short)l;
    }
    const size_t didx = (((size_t)(b * 24 + kb)) * NPIX + p4 * 4 + pp) * 8;
    *(bf16x8*)(F + didx) = hv;
    *(bf16x8*)(F + lo + didx) = lv;
  }
}

// ---------------------------------------------------------------------------
// MFMA GEMM (split-bf16, AhBh+AhBl+AlBh), frag-layout A and B, no LDS.
// ---------------------------------------------------------------------------
__global__ __launch_bounds__(256) void mfma_gemm(
    const unsigned short* __restrict__ BF, size_t b_lo,
    const unsigned short* __restrict__ WF, size_t w_lo,
    int w_bstride,
    float* __restrict__ Out) {
  const int bn = blockIdx.x;
  const int bm = blockIdx.y;
  const int b = blockIdx.z;
  const int t = threadIdx.x;
  const int lane = t & 63, wid = t >> 6;
  const int wm = wid >> 1, wn = wid & 1;

  const size_t wbase = (size_t)b * w_bstride;
  bf16x8 Ah[2][6], Al[2][6];
#pragma unroll
  for (int mi = 0; mi < 2; ++mi) {
    const int mf = bm * 4 + wm * 2 + mi;
#pragma unroll
    for (int ks = 0; ks < 6; ++ks) {
      const size_t idx = wbase + (((size_t)(mf * 6 + ks)) * 64 + lane) * 8;
      Ah[mi][ks] = *(const bf16x8*)(WF + idx);
      Al[mi][ks] = *(const bf16x8*)(WF + w_lo + idx);
    }
  }

  f32x4 acc[2][4];
#pragma unroll
  for (int mi = 0; mi < 2; ++mi)
#pragma unroll
    for (int ni = 0; ni < 4; ++ni) acc[mi][ni] = (f32x4){0.f, 0.f, 0.f, 0.f};

  const int pcol = bn * 128 + wn * 64 + (lane & 15);
  const int kq = lane >> 4;
  const size_t bbase = (size_t)b * CDIM * NPIX;

#pragma unroll
  for (int ks = 0; ks < 6; ++ks) {
    bf16x8 Bh[4], Bl[4];
#pragma unroll
    for (int ni = 0; ni < 4; ++ni) {
      const size_t idx = bbase + (((size_t)(ks * 4 + kq)) * NPIX + pcol + ni * 16) * 8;
      Bh[ni] = *(const bf16x8*)(BF + idx);
      Bl[ni] = *(const bf16x8*)(BF + b_lo + idx);
    }
#pragma unroll
    for (int mi = 0; mi < 2; ++mi)
#pragma unroll
      for (int ni = 0; ni < 4; ++ni) {
        acc[mi][ni] = __builtin_amdgcn_mfma_f32_16x16x32_bf16(
            Ah[mi][ks], Bh[ni], acc[mi][ni], 0, 0, 0);
        acc[mi][ni] = __builtin_amdgcn_mfma_f32_16x16x32_bf16(
            Ah[mi][ks], Bl[ni], acc[mi][ni], 0, 0, 0);
        acc[mi][ni] = __builtin_amdgcn_mfma_f32_16x16x32_bf16(
            Al[mi][ks], Bh[ni], acc[mi][ni], 0, 0, 0);
      }
  }

  const int ocol = bn * 128 + wn * 64 + (lane & 15);
  const int orow = bm * 64 + wm * 32 + (lane >> 4) * 4;
#pragma unroll
  for (int mi = 0; mi < 2; ++mi)
#pragma unroll
    for (int r = 0; r < 4; ++r) {
      const int och = orow + mi * 16 + r;
      float* dst = Out + ((size_t)b * CDIM + och) * NPIX + ocol;
#pragma unroll
      for (int ni = 0; ni < 4; ++ni) dst[ni * 16] = acc[mi][ni][r];
    }
}

// ---------------------------------------------------------------------------
// Fused depthwise-conv + gram partials. Block = (bh, image row).
// Phase 1: conv 24 q-ch + 24 k-ch for this row (reads t0q/t0k global, zero
//          pad, weights scalar) -> LDS [24][132] per tensor.
// Phase 2: 24x24 cross-gram + self-dots over the row's 128 px; 16-lane
//          shuffle reduce; one partial per row.
// ---------------------------------------------------------------------------
__global__ __launch_bounds__(256) void dots_conv(const float* __restrict__ T0Q,
                                                 const float* __restrict__ T0K,
                                                 const float* __restrict__ QDW,
                                                 const float* __restrict__ KDW,
                                                 float* __restrict__ Part) {
  const int bh = blockIdx.x;
  const int row = blockIdx.y;
  const int b = bh >> 3, h = bh & 7;
  const int t = threadIdx.x;
  __shared__ float cq[CH][132];
  __shared__ float ck[CH][132];

  // Phase 1: 768 tasks = (tensor, kb 0..2, px 0..127); 3 iterations.
#pragma unroll
  for (int it = 0; it < 3; ++it) {
    const int task = it * 256 + t;
    const int tensor = task / 384;
    const int rem = task - tensor * 384;
    const int kb = rem >> 7;
    const int px = rem & 127;
    const float* T0 = tensor ? T0K : T0Q;
    const float* DW = tensor ? KDW : QDW;
    float* outp = tensor ? &ck[0][0] : &cq[0][0];
#pragma unroll
    for (int j = 0; j < 8; ++j) {
      const int ch = h * CH + kb * 8 + j;
      const float* w = DW + ch * 9;
      const float* base = T0 + ((size_t)(b * CDIM + ch)) * NPIX + row * WW + px;
      float s = 0.f;
#pragma unroll
      for (int dy = 0; dy < 3; ++dy) {
        const int yy = row + dy - 1;
        if (yy < 0 || yy > 127) continue;          // block-uniform branch
        const float* rp = base + (dy - 1) * WW;
        const float l = (px > 0) ? rp[-1] : 0.f;
        const float m = rp[0];
        const float r = (px < 127) ? rp[1] : 0.f;
        s += w[dy * 3] * l + w[dy * 3 + 1] * m + w[dy * 3 + 2] * r;
      }
      outp[(kb * 8 + j) * 132 + px] = s;
    }
  }
  __syncthreads();

  // Phase 2: gram over 128 px (32 float4; pg covers 16 per iter).
  const int pg = t & 15, sb = t >> 4;
  const int sr = sb >> 2, sc = sb & 3;
  const bool diag = (sr == sc);

  float acc[6][6];
#pragma unroll
  for (int j = 0; j < 6; ++j)
#pragma unroll
    for (int c = 0; c < 6; ++c) acc[j][c] = 0.f;
  float qq[6] = {0, 0, 0, 0, 0, 0};
  float kk[6] = {0, 0, 0, 0, 0, 0};

#pragma unroll
  for (int i = 0; i < 2; ++i) {
    const int f = i * 16 + pg;
    float4 qv[6], kv[6];
#pragma unroll
    for (int j = 0; j < 6; ++j) qv[j] = *(const float4*)&cq[sr * 6 + j][f * 4];
#pragma unroll
    for (int j = 0; j < 6; ++j) kv[j] = *(const float4*)&ck[sc * 6 + j][f * 4];
#pragma unroll
    for (int j = 0; j < 6; ++j)
#pragma unroll
      for (int c = 0; c < 6; ++c)
        acc[j][c] += qv[j].x * kv[c].x + qv[j].y * kv[c].y +
                     qv[j].z * kv[c].z + qv[j].w * kv[c].w;
    if (diag) {
#pragma unroll
      for (int j = 0; j < 6; ++j) {
        qq[j] += qv[j].x * qv[j].x + qv[j].y * qv[j].y + qv[j].z * qv[j].z +
                 qv[j].w * qv[j].w;
        kk[j] += kv[j].x * kv[j].x + kv[j].y * kv[j].y + kv[j].z * kv[j].z +
                 kv[j].w * kv[j].w;
      }
    }
  }

#pragma unroll
  for (int j = 0; j < 6; ++j)
#pragma unroll
    for (int c = 0; c < 6; ++c) {
      float v = acc[j][c];
      v += __shfl_xor(v, 1);
      v += __shfl_xor(v, 2);
      v += __shfl_xor(v, 4);
      v += __shfl_xor(v, 8);
      acc[j][c] = v;
    }
#pragma unroll
  for (int j = 0; j < 6; ++j) {
    float a = qq[j], bb = kk[j];
    a += __shfl_xor(a, 1); a += __shfl_xor(a, 2);
    a += __shfl_xor(a, 4); a += __shfl_xor(a, 8);
    bb += __shfl_xor(bb, 1); bb += __shfl_xor(bb, 2);
    bb += __shfl_xor(bb, 4); bb += __shfl_xor(bb, 8);
    qq[j] = a; kk[j] = bb;
  }

  if (pg == 0) {
    float* P = Part + ((size_t)bh * NSLAB + row) * NJOBS;
#pragma unroll
    for (int j = 0; j < 6; ++j)
#pragma unroll
      for (int c = 0; c < 6; ++c)
        P[(sr * 6 + j) * 24 + sc * 6 + c] = acc[j][c];
    if (diag) {
#pragma unroll
      for (int j = 0; j < 6; ++j) {
        P[576 + sr * 6 + j] = qq[j];
        P[600 + sc * 6 + j] = kk[j];
      }
    }
  }
}

__global__ __launch_bounds__(640) void dots_reduce(const float* __restrict__ Part,
                                                   float* __restrict__ S) {
  const int bh = blockIdx.x;
  const int job = threadIdx.x;
  if (job >= NJOBS) return;
  float s = 0.f;
  for (int i = 0; i < NSLAB; ++i)
    s += Part[((size_t)bh * NSLAB + i) * NJOBS + job];
  S[bh * NJOBS + job] = s;
}

// ---------------------------------------------------------------------------
// Fused depthwise-conv (v path) writing split-bf16 B-fragment layout.
// Block = (b, kb 0..23, row); thread = px. 8 ch/thread -> one bf16x8 hi + lo
// store, 16 B/lane coalesced.
// ---------------------------------------------------------------------------
__global__ __launch_bounds__(128) void dwconv_vf(const float* __restrict__ T0V,
                                                 const float* __restrict__ VDW,
                                                 unsigned short* __restrict__ VF) {
  const int gid = blockIdx.x;
  const int row = gid & 127;
  const int kb = (gid >> 7) % 24;
  const int b = gid / (128 * 24);
  const int px = threadIdx.x;
  const size_t lo = (size_t)BATCH * CDIM * NPIX;

  float v[8];
#pragma unroll
  for (int j = 0; j < 8; ++j) {
    const int ch = kb * 8 + j;
    const float* w = VDW + ch * 9;
    const float* base = T0V + ((size_t)(b * CDIM + ch)) * NPIX + row * WW + px;
    float s = 0.f;
#pragma unroll
    for (int dy = 0; dy < 3; ++dy) {
      const int yy = row + dy - 1;
      if (yy < 0 || yy > 127) continue;
      const float* rp = base + (dy - 1) * WW;
      const float l = (px > 0) ? rp[-1] : 0.f;
      const float m = rp[0];
      const float r = (px < 127) ? rp[1] : 0.f;
      s += w[dy * 3] * l + w[dy * 3 + 1] * m + w[dy * 3 + 2] * r;
    }
    v[j] = s;
  }

  bf16x8 hv, lv;
#pragma unroll
  for (int j = 0; j < 8; ++j) {
    unsigned short h, l;
    f32_split(v[j], h, l);
    hv[j] = (short)h;
    lv[j] = (short)l;
  }
  const size_t didx = (((size_t)(b * 24 + kb)) * NPIX + row * WW + px) * 8;
  *(bf16x8*)(VF + didx) = hv;
  *(bf16x8*)(VF + lo + didx) = lv;
}

// ---------------------------------------------------------------------------
// Normalize, softmax, fold proj: M_b = proj_w @ blockdiag(attn_b).
// ---------------------------------------------------------------------------
__global__ __launch_bounds__(576) void build_M(const float* __restrict__ S,
                                               const float* __restrict__ PW,
                                               const float* __restrict__ Temp,
                                               float* __restrict__ M) {
  const int b = blockIdx.x, h = blockIdx.y;
  const int bh = b * 8 + h;
  __shared__ float att[CH][CH];
  __shared__ float qn[CH], kn[CH];
  const int t = threadIdx.x;
  const float* Sb = S + (size_t)bh * NJOBS;

  if (t < CH) {
    qn[t] = fmaxf(sqrtf(Sb[576 + t]), 1e-12f);
    kn[t] = fmaxf(sqrtf(Sb[600 + t]), 1e-12f);
  }
  __syncthreads();
  const float temp = Temp[h];
  if (t < 576) {
    const int c = t / 24, d = t % 24;
    att[c][d] = Sb[t] / (qn[c] * kn[d]) * temp;
  }
  __syncthreads();
  if (t < CH) {
    float mx = -1e30f;
    for (int d = 0; d < CH; ++d) mx = fmaxf(mx, att[t][d]);
    float sum = 0.f;
    for (int d = 0; d < CH; ++d) {
      const float e = __expf(att[t][d] - mx);
      att[t][d] = e;
      sum += e;
    }
    const float inv = 1.f / sum;
    for (int d = 0; d < CH; ++d) att[t][d] *= inv;
  }
  __syncthreads();
  for (int i = t; i < CDIM * CH; i += 576) {
    const int o = i / CH, d = i % CH;
    float s = 0.f;
#pragma unroll
    for (int c = 0; c < CH; ++c) s += PW[o * CDIM + h * CH + c] * att[c][d];
    M[((size_t)b * CDIM + o) * CDIM + h * CH + d] = s;
  }
}

// ---------------------------------------------------------------------------

extern "C" void kernel_launch(void* const* d_in, const int* in_sizes, int n_in,
                              void* d_out, int out_size, void* d_ws, size_t ws_size,
                              hipStream_t stream) {
  const float* x_feat = (const float*)d_in[0];
  const float* y_feat = (const float*)d_in[1];
  const float* q_pw   = (const float*)d_in[2];
  const float* q_dw   = (const float*)d_in[3];
  const float* k_pw   = (const float*)d_in[4];
  const float* k_dw   = (const float*)d_in[5];
  const float* v_pw   = (const float*)d_in[6];
  const float* v_dw   = (const float*)d_in[7];
  const float* proj_w = (const float*)d_in[8];
  const float* temp   = (const float*)d_in[9];
  float* out = (float*)d_out;

  unsigned char* pool;
  hipGetSymbolAddress((void**)&pool, HIP_SYMBOL(g_pool));
  unsigned short* XF = (unsigned short*)(pool + OFF_XF);
  unsigned short* YF = (unsigned short*)(pool + OFF_YF);
  float* t0q = (float*)(pool + OFF_T0Q);
  float* t0k = (float*)(pool + OFF_T0K);
  float* t0v = (float*)(pool + OFF_T0V);
  unsigned short* VF = (unsigned short*)(pool + OFF_VF);
  float* part = (float*)(pool + OFF_PART);
  float* S    = (float*)(pool + OFF_S);
  float* M    = (float*)(pool + OFF_M);
  unsigned short* MF = (unsigned short*)(pool + OFF_MF);

  unsigned short* WQF = MF + 2ull * 8 * CDIM * CDIM;
  unsigned short* WKF = WQF + 2ull * CDIM * CDIM;
  unsigned short* WVF = WKF + 2ull * CDIM * CDIM;

  const size_t act_lo = (size_t)BATCH * CDIM * NPIX;
  const size_t w1_lo  = (size_t)1 * CDIM * CDIM;
  const size_t w8_lo  = (size_t)8 * CDIM * CDIM;

  const dim3 ggrid(NPIX / 128, 3, BATCH);
  const int fgrid = (BATCH * 24 * NP4) / 256;          // 3072

  // weight conversions (tiny)
  w_to_frag<<<12, 64, 0, stream>>>(q_pw, WQF, 1);
  w_to_frag<<<12, 64, 0, stream>>>(k_pw, WKF, 1);
  w_to_frag<<<12, 64, 0, stream>>>(v_pw, WVF, 1);
  // activation conversions (network inputs only)
  x_to_frag<<<fgrid, 256, 0, stream>>>(x_feat, XF);
  x_to_frag<<<fgrid, 256, 0, stream>>>(y_feat, YF);

  // pointwise GEMMs (pre-conv tensors)
  mfma_gemm<<<ggrid, 256, 0, stream>>>(XF, act_lo, WQF, w1_lo, 0, t0q);
  mfma_gemm<<<ggrid, 256, 0, stream>>>(YF, act_lo, WKF, w1_lo, 0, t0k);
  mfma_gemm<<<ggrid, 256, 0, stream>>>(YF, act_lo, WVF, w1_lo, 0, t0v);

  // fused conv + gram partials (q,k never materialized)
  dots_conv<<<dim3(64, NSLAB), 256, 0, stream>>>(t0q, t0k, q_dw, k_dw, part);
  dots_reduce<<<64, 640, 0, stream>>>(part, S);
  build_M<<<dim3(BATCH, HEADS), 576, 0, stream>>>(S, proj_w, temp, M);
  w_to_frag<<<8 * 12, 64, 0, stream>>>(M, MF, 8);

  // fused conv (v) -> split-bf16 fragment layout
  dwconv_vf<<<BATCH * 24 * 128, 128, 0, stream>>>(t0v, v_dw, VF);

  // out = M_b @ v
  mfma_gemm<<<ggrid, 256, 0, stream>>>(VF, act_lo, MF, w8_lo, CDIM * CDIM, out);
}

// Round 5
// 509.204 us; speedup vs baseline: 1.6955x; 1.6955x over previous
//
#include <hip/hip_runtime.h>
#include <hip/hip_bf16.h>

#define BATCH 8
#define CDIM 192
#define HEADS 8
#define CH 24
#define HH 128
#define WW 128
#define NPIX (HH*WW)                  // 16384
#define NELEM (BATCH*CDIM*NPIX)       // 25165824
#define NP4 (NPIX/4)                  // 4096

#define NSLAB 32
#define NJOBS 624                     // 576 cross dots + 24 q self + 24 k self

typedef __attribute__((ext_vector_type(8))) short bf16x8;
typedef __attribute__((ext_vector_type(4))) float f32x4;

// ---------------------------------------------------------------------------
// Static pool: t0, q, k, v (fp32, 96 MiB each) + misc tail.
// ---------------------------------------------------------------------------
#define UNIT 100663296ull
__device__ __align__(256) unsigned char g_pool[4 * UNIT + (16u << 20)];

#define OFF_T0   (0 * UNIT)
#define OFF_Q    (1 * UNIT)
#define OFF_K    (2 * UNIT)
#define OFF_V    (3 * UNIT)
#define OFF_MISC (4 * UNIT)
#define OFF_PART (OFF_MISC)                            // 64*32*624*4 = 5111808
#define OFF_S    (OFF_MISC + 5111808ull)               // 64*624*4   = 159744
#define OFF_M    (OFF_S + 159744ull)                   // 8*192*192*4 = 1179648
#define OFF_MF   (OFF_M + 1179648ull)                  // hi+lo bf16  = 1179648

// round-to-nearest-even fp32 -> bf16 (bit pattern)
__device__ inline unsigned short bf_rne(float x) {
  unsigned u = __float_as_uint(x);
  unsigned r = (u + 0x7fffu + ((u >> 16) & 1u)) >> 16;
  return (unsigned short)r;
}
__device__ inline void f32_split(float x, unsigned short& h, unsigned short& l) {
  h = bf_rne(x);
  float hf = __uint_as_float(((unsigned)h) << 16);
  l = bf_rne(x - hf);
}

// ---------------------------------------------------------------------------
// Weight/M -> A-fragment layout (hi at base, lo at +nb*CDIM*CDIM elems).
// F_hi[(((b*12+mf)*6+ks)*64+lane)*8+j] = bf16_hi(W[b][mf*16+(lane&15)]
//                                                [ks*32+(lane>>4)*8+j])
// ---------------------------------------------------------------------------
__global__ __launch_bounds__(64) void w_to_frag(const float* __restrict__ W,
                                                unsigned short* __restrict__ F,
                                                int nb) {
  const int b = blockIdx.x / 12, mf = blockIdx.x % 12;
  const int lane = threadIdx.x;
  const int row = mf * 16 + (lane & 15);
  const size_t lo = (size_t)nb * CDIM * CDIM;
#pragma unroll
  for (int ks = 0; ks < 6; ++ks) {
    const int k0 = ks * 32 + (lane >> 4) * 8;
    const float* src = W + ((size_t)b * CDIM + row) * CDIM + k0;
    bf16x8 hv, lv;
#pragma unroll
    for (int j = 0; j < 8; ++j) {
      unsigned short h, l;
      f32_split(src[j], h, l);
      hv[j] = (short)h;
      lv[j] = (short)l;
    }
    const size_t didx = (((size_t)(blockIdx.x) * 6 + ks) * 64 + lane) * 8;
    *(bf16x8*)(F + didx) = hv;
    *(bf16x8*)(F + lo + didx) = lv;
  }
}

// ---------------------------------------------------------------------------
// MFMA GEMM reading fp32 activations directly (no pre-conversion pass).
// Out[b,o,p] = sum_c W[o,c] X[b,c,p]; split-bf16 AhBh+AhBl+AlBh.
// Block 256 thr = 4 waves (2 wm x 2 wn); M=64, N=128 px, BK=32 (6 K-tiles).
// Per K-tile: stage fp32 [32][132] in LDS -> per-lane hi/lo split -> MFMA.
// A-frags loaded per K-tile (L2-hot) to keep VGPR low.
// ---------------------------------------------------------------------------
__global__ __launch_bounds__(256) void mfma_gemm_f32(
    const float* __restrict__ X,
    const unsigned short* __restrict__ WF, size_t w_lo,
    int w_bstride,
    float* __restrict__ Out) {
  const int bn = blockIdx.x;  // 0..127 pixel tile
  const int bm = blockIdx.y;  // 0..2 M tile
  const int b = blockIdx.z;
  const int t = threadIdx.x;
  const int lane = t & 63, wid = t >> 6;
  const int wm = wid >> 1, wn = wid & 1;
  const int kq = lane >> 4;

  __shared__ float Xs[32][132];

  const size_t wbase = (size_t)b * w_bstride;
  const float* Xb = X + (size_t)b * CDIM * NPIX;
  const int col4 = (t & 31) * 4;
  const int r0 = t >> 5;
  const int pxl = wn * 64 + (lane & 15);

  f32x4 acc[2][4];
#pragma unroll
  for (int mi = 0; mi < 2; ++mi)
#pragma unroll
    for (int ni = 0; ni < 4; ++ni) acc[mi][ni] = (f32x4){0.f, 0.f, 0.f, 0.f};

  for (int ks = 0; ks < 6; ++ks) {
    // A-fragments for this K-tile (tiny, L2-served)
    bf16x8 Ah[2], Al[2];
#pragma unroll
    for (int mi = 0; mi < 2; ++mi) {
      const int mf = bm * 4 + wm * 2 + mi;
      const size_t idx = wbase + (((size_t)(mf * 6 + ks)) * 64 + lane) * 8;
      Ah[mi] = *(const bf16x8*)(WF + idx);
      Al[mi] = *(const bf16x8*)(WF + w_lo + idx);
    }

    // stage fp32 tile 32 x 128
#pragma unroll
    for (int p = 0; p < 4; ++p) {
      const int r = r0 + 8 * p;
      *(float4*)&Xs[r][col4] =
          *(const float4*)(Xb + (size_t)(ks * 32 + r) * NPIX + bn * 128 + col4);
    }
    __syncthreads();

    // per-lane conversion to B fragments
    bf16x8 Bh[4], Bl[4];
#pragma unroll
    for (int ni = 0; ni < 4; ++ni) {
      const int px = pxl + ni * 16;
#pragma unroll
      for (int j = 0; j < 8; ++j) {
        unsigned short h, l;
        f32_split(Xs[kq * 8 + j][px], h, l);
        Bh[ni][j] = (short)h;
        Bl[ni][j] = (short)l;
      }
    }
    __syncthreads();

#pragma unroll
    for (int mi = 0; mi < 2; ++mi)
#pragma unroll
      for (int ni = 0; ni < 4; ++ni) {
        acc[mi][ni] = __builtin_amdgcn_mfma_f32_16x16x32_bf16(
            Ah[mi], Bh[ni], acc[mi][ni], 0, 0, 0);
        acc[mi][ni] = __builtin_amdgcn_mfma_f32_16x16x32_bf16(
            Ah[mi], Bl[ni], acc[mi][ni], 0, 0, 0);
        acc[mi][ni] = __builtin_amdgcn_mfma_f32_16x16x32_bf16(
            Al[mi], Bh[ni], acc[mi][ni], 0, 0, 0);
      }
  }

  const int ocol = bn * 128 + wn * 64 + (lane & 15);
  const int orow = bm * 64 + wm * 32 + (lane >> 4) * 4;
#pragma unroll
  for (int mi = 0; mi < 2; ++mi)
#pragma unroll
    for (int r = 0; r < 4; ++r) {
      const int och = orow + mi * 16 + r;
      float* dst = Out + ((size_t)b * CDIM + och) * NPIX + ocol;
#pragma unroll
      for (int ni = 0; ni < 4; ++ni) dst[ni * 16] = acc[mi][ni][r];
    }
}

// ---------------------------------------------------------------------------
// Depthwise 3x3 conv, zero pad (fp32 in/out, channel-major).
// ---------------------------------------------------------------------------
__global__ __launch_bounds__(256) void dwconv(const float* __restrict__ In,
                                              const float* __restrict__ Wd,
                                              float* __restrict__ Out) {
  const int idx = blockIdx.x * 256 + threadIdx.x;
  if (idx >= NELEM / 4) return;
  const int x4 = (idx & 31) * 4;
  const int y = (idx >> 5) & 127;
  const int c = (idx >> 12) % CDIM;
  const int b = idx / (32 * 128 * CDIM);

  const float* base = In + (size_t)(b * CDIM + c) * NPIX;
  float w[9];
#pragma unroll
  for (int i = 0; i < 9; ++i) w[i] = Wd[c * 9 + i];

  float acc0 = 0.f, acc1 = 0.f, acc2 = 0.f, acc3 = 0.f;
#pragma unroll
  for (int dy = 0; dy < 3; ++dy) {
    const int yy = y + dy - 1;
    if (yy < 0 || yy > 127) continue;
    const float* row = base + yy * WW;
    float vb0 = (x4 > 0) ? row[x4 - 1] : 0.f;
    const float4 m = *(const float4*)(row + x4);
    const float vb5 = (x4 + 4 < WW) ? row[x4 + 4] : 0.f;
    const float w0 = w[dy * 3 + 0], w1 = w[dy * 3 + 1], w2 = w[dy * 3 + 2];
    acc0 += w0 * vb0 + w1 * m.x + w2 * m.y;
    acc1 += w0 * m.x + w1 * m.y + w2 * m.z;
    acc2 += w0 * m.y + w1 * m.z + w2 * m.w;
    acc3 += w0 * m.z + w1 * m.w + w2 * vb5;
  }
  float4 o;
  o.x = acc0; o.y = acc1; o.z = acc2; o.w = acc3;
  *(float4*)(Out + (size_t)idx * 4) = o;
}

// ---------------------------------------------------------------------------
// Gram dots: register outer-product, no LDS (R3 structure, NSLAB=32).
// ---------------------------------------------------------------------------
__global__ __launch_bounds__(256) void dots_partial(const float* __restrict__ Q,
                                                    const float* __restrict__ K,
                                                    float* __restrict__ Part) {
  const int bh = blockIdx.x;
  const int slab = blockIdx.y;
  const int b = bh >> 3, h = bh & 7;
  const int t = threadIdx.x;
  const int pg = t & 15;
  const int sb = t >> 4;
  const int sr = sb >> 2, sc = sb & 3;
  const bool diag = (sr == sc);

  const float4* qb = (const float4*)(Q + (size_t)(b * CDIM + h * CH) * NPIX);
  const float4* kb = (const float4*)(K + (size_t)(b * CDIM + h * CH) * NPIX);
  const int F_PER_SLAB = NP4 / NSLAB;       // 128
  const int NITER = F_PER_SLAB / 16;        // 8

  float acc[6][6];
#pragma unroll
  for (int j = 0; j < 6; ++j)
#pragma unroll
    for (int c = 0; c < 6; ++c) acc[j][c] = 0.f;
  float qq[6] = {0, 0, 0, 0, 0, 0};
  float kk[6] = {0, 0, 0, 0, 0, 0};

  const int f0 = slab * F_PER_SLAB + pg;
  for (int i = 0; i < NITER; ++i) {
    const int f = f0 + 16 * i;
    float4 qv[6], kv[6];
#pragma unroll
    for (int j = 0; j < 6; ++j) qv[j] = qb[(size_t)(sr * 6 + j) * NP4 + f];
#pragma unroll
    for (int j = 0; j < 6; ++j) kv[j] = kb[(size_t)(sc * 6 + j) * NP4 + f];
#pragma unroll
    for (int j = 0; j < 6; ++j)
#pragma unroll
      for (int c = 0; c < 6; ++c)
        acc[j][c] += qv[j].x * kv[c].x + qv[j].y * kv[c].y +
                     qv[j].z * kv[c].z + qv[j].w * kv[c].w;
    if (diag) {
#pragma unroll
      for (int j = 0; j < 6; ++j) {
        qq[j] += qv[j].x * qv[j].x + qv[j].y * qv[j].y + qv[j].z * qv[j].z +
                 qv[j].w * qv[j].w;
        kk[j] += kv[j].x * kv[j].x + kv[j].y * kv[j].y + kv[j].z * kv[j].z +
                 kv[j].w * kv[j].w;
      }
    }
  }

#pragma unroll
  for (int j = 0; j < 6; ++j)
#pragma unroll
    for (int c = 0; c < 6; ++c) {
      float v = acc[j][c];
      v += __shfl_xor(v, 1);
      v += __shfl_xor(v, 2);
      v += __shfl_xor(v, 4);
      v += __shfl_xor(v, 8);
      acc[j][c] = v;
    }
#pragma unroll
  for (int j = 0; j < 6; ++j) {
    float a = qq[j], bb = kk[j];
    a += __shfl_xor(a, 1); a += __shfl_xor(a, 2);
    a += __shfl_xor(a, 4); a += __shfl_xor(a, 8);
    bb += __shfl_xor(bb, 1); bb += __shfl_xor(bb, 2);
    bb += __shfl_xor(bb, 4); bb += __shfl_xor(bb, 8);
    qq[j] = a; kk[j] = bb;
  }

  if (pg == 0) {
    float* P = Part + ((size_t)bh * NSLAB + slab) * NJOBS;
#pragma unroll
    for (int j = 0; j < 6; ++j)
#pragma unroll
      for (int c = 0; c < 6; ++c)
        P[(sr * 6 + j) * 24 + sc * 6 + c] = acc[j][c];
    if (diag) {
#pragma unroll
      for (int j = 0; j < 6; ++j) {
        P[576 + sr * 6 + j] = qq[j];
        P[600 + sc * 6 + j] = kk[j];
      }
    }
  }
}

__global__ __launch_bounds__(640) void dots_reduce(const float* __restrict__ Part,
                                                   float* __restrict__ S) {
  const int bh = blockIdx.x;
  const int job = threadIdx.x;
  if (job >= NJOBS) return;
  float s = 0.f;
  for (int i = 0; i < NSLAB; ++i)
    s += Part[((size_t)bh * NSLAB + i) * NJOBS + job];
  S[bh * NJOBS + job] = s;
}

// ---------------------------------------------------------------------------
// Normalize, softmax, fold proj: M_b = proj_w @ blockdiag(attn_b).
// ---------------------------------------------------------------------------
__global__ __launch_bounds__(576) void build_M(const float* __restrict__ S,
                                               const float* __restrict__ PW,
                                               const float* __restrict__ Temp,
                                               float* __restrict__ M) {
  const int b = blockIdx.x, h = blockIdx.y;
  const int bh = b * 8 + h;
  __shared__ float att[CH][CH];
  __shared__ float qn[CH], kn[CH];
  const int t = threadIdx.x;
  const float* Sb = S + (size_t)bh * NJOBS;

  if (t < CH) {
    qn[t] = fmaxf(sqrtf(Sb[576 + t]), 1e-12f);
    kn[t] = fmaxf(sqrtf(Sb[600 + t]), 1e-12f);
  }
  __syncthreads();
  const float temp = Temp[h];
  if (t < 576) {
    const int c = t / 24, d = t % 24;
    att[c][d] = Sb[t] / (qn[c] * kn[d]) * temp;
  }
  __syncthreads();
  if (t < CH) {
    float mx = -1e30f;
    for (int d = 0; d < CH; ++d) mx = fmaxf(mx, att[t][d]);
    float sum = 0.f;
    for (int d = 0; d < CH; ++d) {
      const float e = __expf(att[t][d] - mx);
      att[t][d] = e;
      sum += e;
    }
    const float inv = 1.f / sum;
    for (int d = 0; d < CH; ++d) att[t][d] *= inv;
  }
  __syncthreads();
  for (int i = t; i < CDIM * CH; i += 576) {
    const int o = i / CH, d = i % CH;
    float s = 0.f;
#pragma unroll
    for (int c = 0; c < CH; ++c) s += PW[o * CDIM + h * CH + c] * att[c][d];
    M[((size_t)b * CDIM + o) * CDIM + h * CH + d] = s;
  }
}

// ---------------------------------------------------------------------------

extern "C" void kernel_launch(void* const* d_in, const int* in_sizes, int n_in,
                              void* d_out, int out_size, void* d_ws, size_t ws_size,
                              hipStream_t stream) {
  const float* x_feat = (const float*)d_in[0];
  const float* y_feat = (const float*)d_in[1];
  const float* q_pw   = (const float*)d_in[2];
  const float* q_dw   = (const float*)d_in[3];
  const float* k_pw   = (const float*)d_in[4];
  const float* k_dw   = (const float*)d_in[5];
  const float* v_pw   = (const float*)d_in[6];
  const float* v_dw   = (const float*)d_in[7];
  const float* proj_w = (const float*)d_in[8];
  const float* temp   = (const float*)d_in[9];
  float* out = (float*)d_out;

  unsigned char* pool;
  hipGetSymbolAddress((void**)&pool, HIP_SYMBOL(g_pool));
  float* t0 = (float*)(pool + OFF_T0);
  float* q  = (float*)(pool + OFF_Q);
  float* k  = (float*)(pool + OFF_K);
  float* v  = (float*)(pool + OFF_V);
  float* part = (float*)(pool + OFF_PART);
  float* S    = (float*)(pool + OFF_S);
  float* M    = (float*)(pool + OFF_M);
  unsigned short* MF = (unsigned short*)(pool + OFF_MF);

  unsigned short* WQF = MF + 2ull * 8 * CDIM * CDIM;
  unsigned short* WKF = WQF + 2ull * CDIM * CDIM;
  unsigned short* WVF = WKF + 2ull * CDIM * CDIM;

  const size_t w1_lo = (size_t)1 * CDIM * CDIM;
  const size_t w8_lo = (size_t)8 * CDIM * CDIM;

  const dim3 ggrid(NPIX / 128, 3, BATCH);
  const int dwgrid = (NELEM / 4) / 256;

  // weight conversions (tiny)
  w_to_frag<<<12, 64, 0, stream>>>(q_pw, WQF, 1);
  w_to_frag<<<12, 64, 0, stream>>>(k_pw, WKF, 1);
  w_to_frag<<<12, 64, 0, stream>>>(v_pw, WVF, 1);

  // q/k/v = dw(pw(...)), GEMMs read fp32 directly
  mfma_gemm_f32<<<ggrid, 256, 0, stream>>>(x_feat, WQF, w1_lo, 0, t0);
  dwconv<<<dwgrid, 256, 0, stream>>>(t0, q_dw, q);
  mfma_gemm_f32<<<ggrid, 256, 0, stream>>>(y_feat, WKF, w1_lo, 0, t0);
  dwconv<<<dwgrid, 256, 0, stream>>>(t0, k_dw, k);
  mfma_gemm_f32<<<ggrid, 256, 0, stream>>>(y_feat, WVF, w1_lo, 0, t0);
  dwconv<<<dwgrid, 256, 0, stream>>>(t0, v_dw, v);

  // attention gram + softmax + proj fold
  dots_partial<<<dim3(64, NSLAB), 256, 0, stream>>>(q, k, part);
  dots_reduce<<<64, 640, 0, stream>>>(part, S);
  build_M<<<dim3(BATCH, HEADS), 576, 0, stream>>>(S, proj_w, temp, M);
  w_to_frag<<<8 * 12, 64, 0, stream>>>(M, MF, 8);

  // out = M_b @ v (reads fp32 v directly)
  mfma_gemm_f32<<<ggrid, 256, 0, stream>>>(v, MF, w8_lo, CDIM * CDIM, out);
}